// Round 8
// baseline (186.100 us; speedup 1.0000x reference)
//
#include <hip/hip_runtime.h>
#include <math.h>

#define D1 768
#define D2R 385
#define NF 295680   // 768*385
#define KNUM 4
#define NB 8
#define NC 256
#define TWOPI_768 0.008181230868723419f
#define INV768 0.0013020833333333333f

// ---------------- ws layout (bytes) --------------------------------------
// specB  bf16 [4][448 c-rows][1536 k]   @ 0          (6,291,456 B)  B^T stage A
// Atw    bf16 [2][768 m][1536 k]        @ 6,291,456  (4,718,592 B)  A stage A
// Ya     bf16 [4][768 m][800 k]         @ 11,010,048 (4,915,200 B)  A stage B
// T      bf16 [768 n][800 k]            @ 15,925,248 (1,228,800 B)  B^T stage B
// SW     f32  [4][768][768]             @ 0          (9,437,184 B)  overlays specB+Atw (dead)
// wBF    bf16 [8][144 step][2 ih][256 oc][8]  @ 9,437,184 (9,437,184 B) overlays Ya+T
#define ATW_U32 1572864u
#define YA_U32 2752512u
#define T_U32 3981312u
#define SPECB_K_U32 344064u  // 448*768 uints per k
#define WBF_BYTE 9437184u

typedef __attribute__((ext_vector_type(8))) short short8;
typedef __attribute__((ext_vector_type(16))) float f32x16;
union U4S8 { unsigned int u[4]; uint4 u4; short8 s8; };

static __device__ __forceinline__ unsigned int f2bf(float f) {
  unsigned int u = __float_as_uint(f);
  return (u + 0x7fffu + ((u >> 16) & 1u)) >> 16;  // RNE, no NaN inputs
}

// hw sin/cos: v_sin_f32/v_cos_f32 take REVOLUTIONS; idx in [0,768) -> idx/768
static __device__ __forceinline__ void sincos_rev768(int idx, float* s,
                                                     float* c) {
  float rev = (float)idx * INV768;
  *s = __builtin_amdgcn_sinf(rev);
  *c = __builtin_amdgcn_cosf(rev);
}

// raw barrier: LDS-drain only; register-dest vmem loads stay in flight.
static __device__ __forceinline__ void barrier_lgkm() {
  asm volatile("s_waitcnt lgkmcnt(0)" ::: "memory");
  __builtin_amdgcn_sched_barrier(0);
  __builtin_amdgcn_s_barrier();
  __builtin_amdgcn_sched_barrier(0);
}

// ---------------- prep v2: 4 elems/thread, vectorized IO -----------------
__global__ __launch_bounds__(256) void prep_kernel(
    const float* __restrict__ dw, const int* __restrict__ fh,
    const int* __restrict__ fw, unsigned int* __restrict__ ws) {
  int q = blockIdx.x * 256 + threadIdx.x;  // grid 2841 -> 727296 quads
  if (q < 295680) {  // scatter: 4 consecutive r of one k
    int k = q / 73920;
    int ql = q - k * 73920;  // int4 index into fh/fw
    long f2i = (long)k * NF + (long)ql * 4;
    const float4 v0 = ((const float4*)dw)[f2i >> 1];
    const float4 v1 = ((const float4*)dw)[(f2i >> 1) + 1];
    const int4 h4 = ((const int4*)fh)[ql];
    const int4 c4 = ((const int4*)fw)[ql];
    size_t kb = (size_t)k * SPECB_K_U32;
    ws[kb + (size_t)c4.x * 768 + h4.x] = f2bf(v0.x) | (f2bf(v0.y) << 16);
    ws[kb + (size_t)c4.y * 768 + h4.y] = f2bf(v0.z) | (f2bf(v0.w) << 16);
    ws[kb + (size_t)c4.z * 768 + h4.z] = f2bf(v1.x) | (f2bf(v1.y) << 16);
    ws[kb + (size_t)c4.w * 768 + h4.w] = f2bf(v1.z) | (f2bf(v1.w) << 16);
    return;
  }
  int j = q - 295680;
  if (j < 294912) {  // Atw: 4 consecutive h of one (ri,m)
    int j0 = j * 4;  // element index, %4==0
    int ri = j0 / 589824;
    int rem = j0 - ri * 589824;
    int m = rem / 768, h0 = rem - (rem / 768) * 768;
    uint4 o;
#pragma unroll
    for (int e = 0; e < 4; ++e) {
      int idx = ((h0 + e) * m) % 768;
      float s, c;
      sincos_rev768(idx, &s, &c);
      unsigned lo, hi;
      if (ri == 0) { lo = f2bf(c); hi = f2bf(-s); }
      else         { lo = f2bf(s); hi = f2bf(c); }
      ((unsigned*)&o)[e] = lo | (hi << 16);
    }
    *(uint4*)(ws + ATW_U32 + j0) = o;
  } else if (j < 371712) {  // T^T: 4 consecutive cc of one n
    int p0 = (j - 294912) * 4;
    int n = p0 / 400, cc0 = p0 - (p0 / 400) * 400;
    uint4 o;
#pragma unroll
    for (int e = 0; e < 4; ++e) {
      int cc = cc0 + e;
      unsigned v = 0;
      if (cc <= 384) {
        float wgt = (cc == 0 || cc == 384) ? 1.6954210069444445e-6f
                                           : 3.390842013888889e-6f;
        int idx = (cc * n) % 768;
        float s, c;
        sincos_rev768(idx, &s, &c);
        v = f2bf(wgt * c) | (f2bf(-wgt * s) << 16);
      }
      ((unsigned*)&o)[e] = v;
    }
    *(uint4*)(ws + T_U32 + (size_t)n * 400 + cc0) = o;
  } else if (j < 420096) {  // specB zero rows 385..447 (uint4)
    int p0 = (j - 371712) * 4;
    int k = p0 / 48384;
    int r = p0 - k * 48384;
    int row = 385 + r / 768;
    int col = r - (r / 768) * 768;
    *(uint4*)(ws + (size_t)k * SPECB_K_U32 + (size_t)row * 768 + col) =
        make_uint4(0u, 0u, 0u, 0u);
  } else if (j < 431616) {  // Ya zero cols 770..799 (scalar x4: stride 15)
    int p0 = (j - 420096) * 4;
#pragma unroll
    for (int e = 0; e < 4; ++e) {
      int p = p0 + e;
      int k = p / 11520;
      int r = p - k * 11520;
      int m = r / 15, jj = r - (r / 15) * 15;
      ws[YA_U32 + (size_t)k * 307200 + (size_t)m * 400 + 385 + jj] = 0u;
    }
  }
}

// ---------------- fftA v5: 64x64 tile + E/O pipeline, grid 672 -----------
__global__ __launch_bounds__(256) void fftA_kernel(
    const unsigned short* __restrict__ Atw,
    const unsigned short* __restrict__ specB,
    unsigned short* __restrict__ Ya) {
  __shared__ __align__(16) unsigned short Al[2][64 * 40], Bl[2][64 * 40];
  int t = threadIdx.x;
  int mt = blockIdx.x, nt = blockIdx.y, z = blockIdx.z;
  int ri = z & 1, k = z >> 1;
  const unsigned short* Ag =
      Atw + (size_t)ri * 1179648 + (size_t)(mt * 64) * 1536;
  const unsigned short* Bg =
      specB + (size_t)k * 688128 + (size_t)(nt * 64) * 1536;
  int rowS = t >> 2, q = t & 3;
  int lane = t & 63, w = t >> 6;
  int mq = w & 1, nq = w >> 1;
  int lm = lane & 31, half = lane >> 5;
  int wr = rowS * 40 + q * 8;
  int ao = (mq * 32 + lm) * 40 + half * 8;
  int bo = (nq * 32 + lm) * 40 + half * 8;

  f32x16 acc;
#pragma unroll
  for (int r = 0; r < 16; ++r) acc[r] = 0.f;

#define FA_LOAD(da, db, kb)                                              \
  da = *(const uint4*)(Ag + (size_t)rowS * 1536 + (kb) * 32 + q * 8);    \
  db = *(const uint4*)(Bg + (size_t)rowS * 1536 + (kb) * 32 + q * 8);
#define F_WRITE(buf, sa, sb)                                             \
  *(uint4*)&Al[buf][wr] = sa;                                            \
  *(uint4*)&Bl[buf][wr] = sb;
#define F_COMPUTE(buf)                                                   \
  {                                                                      \
    const unsigned short* Ab = Al[buf];                                  \
    const unsigned short* Bb = Bl[buf];                                  \
    _Pragma("unroll") for (int kk2 = 0; kk2 < 2; ++kk2) {                \
      short8 a8 = *(const short8*)&Ab[ao + kk2 * 16];                    \
      short8 b8 = *(const short8*)&Bb[bo + kk2 * 16];                    \
      acc = __builtin_amdgcn_mfma_f32_32x32x16_bf16(a8, b8, acc, 0, 0, 0); \
    }                                                                    \
  }

  uint4 eA, eB, oA, oB;
  FA_LOAD(eA, eB, 0)
  FA_LOAD(oA, oB, 1)
  F_WRITE(0, eA, eB)
  barrier_lgkm();

  const int NK = 48;
  for (int kb = 0; kb < NK; kb += 2) {
    if (kb + 2 < NK) { FA_LOAD(eA, eB, kb + 2) }
    F_COMPUTE(0)
    if (kb + 1 < NK) { F_WRITE(1, oA, oB) }
    barrier_lgkm();
    if (kb + 1 < NK) {
      if (kb + 3 < NK) { FA_LOAD(oA, oB, kb + 3) }
      F_COMPUTE(1)
      if (kb + 2 < NK) { F_WRITE(0, eA, eB) }
      barrier_lgkm();
    }
  }

  int c = nt * 64 + nq * 32 + lm;
  if (c < D2R) {
    unsigned short* Yk = Ya + (size_t)k * 614400;
    int mb = mt * 64 + mq * 32 + 4 * half;
#pragma unroll
    for (int reg = 0; reg < 16; ++reg) {
      int m = mb + (reg & 3) + 8 * (reg >> 2);
      Yk[(size_t)m * 800 + 2 * c + ri] = (unsigned short)f2bf(acc[reg]);
    }
  }
}

// ---------------- fftB v5: 64x64 tile + E/O pipeline, grid 576 -----------
__global__ __launch_bounds__(256) void fftB_kernel(
    const unsigned short* __restrict__ Ya, const unsigned short* __restrict__ T,
    float* __restrict__ SW) {
  __shared__ __align__(16) unsigned short Al[2][64 * 40], Bl[2][64 * 40];
  int t = threadIdx.x;
  int mt = blockIdx.x, nt = blockIdx.y, k = blockIdx.z;
  const unsigned short* Ag = Ya + (size_t)k * 614400 + (size_t)(mt * 64) * 800;
  const unsigned short* Bg = T + (size_t)(nt * 64) * 800;
  int rowS = t >> 2, q = t & 3;
  int lane = t & 63, w = t >> 6;
  int mq = w & 1, nq = w >> 1;
  int lm = lane & 31, half = lane >> 5;
  int wr = rowS * 40 + q * 8;
  int ao = (mq * 32 + lm) * 40 + half * 8;
  int bo = (nq * 32 + lm) * 40 + half * 8;

  f32x16 acc;
#pragma unroll
  for (int r = 0; r < 16; ++r) acc[r] = 0.f;

#define FB_LOAD(da, db, kb)                                             \
  da = *(const uint4*)(Ag + (size_t)rowS * 800 + (kb) * 32 + q * 8);    \
  db = *(const uint4*)(Bg + (size_t)rowS * 800 + (kb) * 32 + q * 8);

  uint4 eA, eB, oA, oB;
  FB_LOAD(eA, eB, 0)
  FB_LOAD(oA, oB, 1)
  F_WRITE(0, eA, eB)
  barrier_lgkm();

  const int NK = 25;
  for (int kb = 0; kb < NK; kb += 2) {
    if (kb + 2 < NK) { FB_LOAD(eA, eB, kb + 2) }
    F_COMPUTE(0)
    if (kb + 1 < NK) { F_WRITE(1, oA, oB) }
    barrier_lgkm();
    if (kb + 1 < NK) {
      if (kb + 3 < NK) { FB_LOAD(oA, oB, kb + 3) }
      F_COMPUTE(1)
      if (kb + 2 < NK) { F_WRITE(0, eA, eB) }
      barrier_lgkm();
    }
  }

  float* SWk = SW + (size_t)k * 589824;
  int n = nt * 64 + nq * 32 + lm;
  int mb = mt * 64 + mq * 32 + 4 * half;
#pragma unroll
  for (int reg = 0; reg < 16; ++reg) {
    int m = mb + (reg & 3) + 8 * (reg >> 2);
    SWk[(size_t)m * 768 + n] = acc[reg];
  }
}

// ---------------- wprep v3: store to [b][step][ih][oc][8] layout ---------
__global__ __launch_bounds__(256) void wprep_kernel(
    const float* __restrict__ ka, const float* __restrict__ SW,
    unsigned short* __restrict__ wBF) {
  __shared__ float rowL[4][768];
  int t = threadIdx.x;
  int row = blockIdx.x;  // grid 768: row = oc*3 + dy
  int oc = row / 3, dy = row - oc * 3;
  if (t < 192) {
#pragma unroll
    for (int k = 0; k < 4; ++k)
      *(float4*)&rowL[k][t * 4] =
          *(const float4*)(SW + (size_t)k * 589824 + (size_t)row * 768 + t * 4);
  }
  float att[8][4];
#pragma unroll
  for (int b = 0; b < 8; ++b)
#pragma unroll
    for (int k = 0; k < 4; ++k)
      att[b][k] = 0.5f / (1.f + expf(-ka[b * 4 + k]));
  __syncthreads();
  int icb = t >> 4, i = t & 15;
  int ih = i >> 3, il = i & 7;
#pragma unroll
  for (int dx = 0; dx < 3; ++dx) {
    int col = icb * 48 + dx + 3 * i;
    float v0 = rowL[0][col], v1 = rowL[1][col], v2 = rowL[2][col],
          v3 = rowL[3][col];
    int s = dy * 3 + dx;
    int step = icb * 9 + s;
#pragma unroll
    for (int b = 0; b < 8; ++b) {
      float v = att[b][0] * v0 + att[b][1] * v1 + att[b][2] * v2 +
                att[b][3] * v3;
      // layout: [b][144 step][2 ih][256 oc][8 il]
      wBF[(((size_t)(b * 144 + step) * 2 + ih) * 256 + oc) * 8 + il] =
          (unsigned short)f2bf(v);
    }
  }
}

// ---------------- conv v10: wBF through LDS (block-shared A-frags) -------
// r7 post-mortem: pf ring = per-WAVE global refills, 1KB/load = 16 lines;
// 2 blk x 8 waves x 18 loads x 16 = 4608 TA lines/CU/icb (2x the 2304-cyc
// MFMA term) -> TA-bound at 30% MfmaUtil. Fix: stage the icb's A-frags
// (9 steps x 2 ih x 128 oc x 16B = 36.9KB) into LDS once per BLOCK via
// 9 coalesced 4KB loads -> 1152 lines/CU/icb (4x cut); waves read frags
// from LDS (consecutive-lane granules, conflict-free). Costs +1 barrier
// per icb (wL write->read fence). MFMA becomes the binding term.
__global__ __launch_bounds__(256, 2) void conv_mfma_kernel(
    const float* __restrict__ x, const unsigned short* __restrict__ wBF,
    float* __restrict__ out) {
  __shared__ __align__(16) unsigned char ldsX[2][4 * 2 * 66 * 16];  // 16896B
  __shared__ __align__(16) unsigned char wL[9 * 2 * 128 * 16];      // 36864B
  int t = threadIdx.x;
  // XCD swizzle: hw round-robins consecutive blockIdx across 8 XCDs.
  int orig = blockIdx.x;  // grid 512
  int xcd = orig & 7, seq = orig >> 3;
  int slice = xcd * 2 + (seq >> 5);  // = b*2 + oct; XCD x owns b = x
  int pxt = seq & 31;
  int b = slice >> 1, oct = slice & 1;
  int py0 = pxt * 2, oc0 = oct * 128;
  int lane = t & 63, w = t >> 6;
  int ocq = w >> 1, pxq = w & 1;
  int n = lane & 31, half = lane >> 5;

  // zero halo granules (px sites 0 and 65; all rows/icg) in both buffers
  if (t < 128) {
    int buf = t >> 6, rem = t & 63;
    int idx = rem >> 2, word = rem & 3;  // 16 sites x 4 words
    int r = idx >> 2, icg = (idx >> 1) & 1, c = (idx & 1) ? 65 : 0;
    *(unsigned int*)(&ldsX[buf][(((r * 2 + icg) * 66) + c) * 16 + word * 4]) =
        0u;
  }

  f32x16 acc[2][2];
#pragma unroll
  for (int i = 0; i < 2; ++i)
#pragma unroll
    for (int j = 0; j < 2; ++j)
#pragma unroll
      for (int r = 0; r < 16; ++r) acc[i][j][r] = 0.f;

  // x staging role: thread owns ic w*4..w*4+3, row sub, px {px4+16pp}
  int px4 = lane & 15, sub = lane >> 4;
  int iy = py0 - 1 + sub;
  bool valid = (iy >= 0 && iy < 64);
  const float* xpb =
      x + (((size_t)(b * NC + w * 4)) * 64 + (valid ? iy : 0)) * 64 + px4;
  int xwbase = (((sub * 2 + (w >> 1)) * 66) + 1 + px4) * 16 + (w & 1) * 8;
  unsigned char* xw0 = (unsigned char*)&ldsX[0][0] + xwbase;
  unsigned char* xw1 = (unsigned char*)&ldsX[1][0] + xwbase;

  // wBF staging role: thread t covers (ih = t>>7, ocl = t&127), one granule
  // per step. Global: [b][step][ih][256 oc][8]; step stride 4096 shorts.
  const unsigned short* wgB = wBF + (size_t)b * 589824 +
                              (size_t)(t >> 7) * 2048 +
                              (size_t)(oc0 + (t & 127)) * 8;
  unsigned char* wlw = wL + ((t >> 7) * 128 + (t & 127)) * 16;  // + s*4096
  // A-frag read base: lane l -> [s][l>>5][ocq*64 + (l&31)]
  const unsigned char* wlr =
      wL + (lane >> 5) * 2048 + (ocq * 64 + (lane & 31)) * 16;  // + s*4096

  uint4 wreg[9];
#define WSTAGE_LOAD(ICB)                                                  \
  _Pragma("unroll") for (int s9 = 0; s9 < 9; ++s9) wreg[s9] =             \
      *(const uint4*)(wgB + (size_t)((ICB) * 9 + s9) * 4096);
#define WSTAGE_WRITE()                                                    \
  _Pragma("unroll") for (int s9 = 0; s9 < 9; ++s9)                        \
      *(uint4*)(wlw + s9 * 4096) = wreg[s9];

  float a[4][4];  // [ic j][pp]
#define XLOAD(ICB)                                                        \
  _Pragma("unroll") for (int j = 0; j < 4; ++j) _Pragma("unroll")         \
      for (int pp = 0; pp < 4; ++pp) a[j][pp] = 0.f;                      \
  if (valid) {                                                            \
    const float* p0 = xpb + (size_t)(ICB) * 16 * 4096;                    \
    _Pragma("unroll") for (int j = 0; j < 4; ++j) {                       \
      const float* pj = p0 + (size_t)j * 4096;                            \
      _Pragma("unroll") for (int pp = 0; pp < 4; ++pp)                    \
          a[j][pp] = pj[pp * 16];                                         \
    }                                                                     \
  }
#define XWRITE(XW)                                                        \
  _Pragma("unroll") for (int pp = 0; pp < 4; ++pp) {                      \
    uint2 wv;                                                             \
    wv.x = f2bf(a[0][pp]) | (f2bf(a[1][pp]) << 16);                       \
    wv.y = f2bf(a[2][pp]) | (f2bf(a[3][pp]) << 16);                       \
    *(uint2*)((XW) + pp * 256) = wv;                                      \
  }

  // prologue: stage icb 0 (wBF + x) into LDS
  WSTAGE_LOAD(0)
  XLOAD(0)
  WSTAGE_WRITE()
  XWRITE(xw0)
  barrier_lgkm();

  for (int icb = 0; icb < 16; ++icb) {
    if (icb < 15) {  // issue next tile's loads (cover = this icb's MFMAs)
      WSTAGE_LOAD(icb + 1)
      XLOAD(icb + 1)
    }
    const unsigned char* bufR = &ldsX[icb & 1][0];
#pragma unroll
    for (int s = 0; s < 9; ++s) {
      int dy = s / 3, dx = s - dy * 3;
      const unsigned char* bb =
          bufR + ((((pxq + dy) * 2 + half) * 66) + n + dx) * 16;
      short8 B0 = *(const short8*)bb;
      short8 B1 = *(const short8*)(bb + 512);
      const unsigned char* wls = wlr + s * 4096;
      short8 A0 = *(const short8*)wls;
      short8 A1 = *(const short8*)(wls + 512);
      acc[0][0] =
          __builtin_amdgcn_mfma_f32_32x32x16_bf16(A0, B0, acc[0][0], 0, 0, 0);
      acc[0][1] =
          __builtin_amdgcn_mfma_f32_32x32x16_bf16(A0, B1, acc[0][1], 0, 0, 0);
      acc[1][0] =
          __builtin_amdgcn_mfma_f32_32x32x16_bf16(A1, B0, acc[1][0], 0, 0, 0);
      acc[1][1] =
          __builtin_amdgcn_mfma_f32_32x32x16_bf16(A1, B1, acc[1][1], 0, 0, 0);
    }
    barrier_lgkm();  // all waves done reading wL (and ldsX[icb&1])
    if (icb < 15) {  // overwrite wL + fill other x buffer
      WSTAGE_WRITE()
      XWRITE((icb & 1) ? xw0 : xw1)
    }
    barrier_lgkm();  // writes visible before next icb's reads
  }

  int py = py0 + pxq;
#pragma unroll
  for (int osub = 0; osub < 2; ++osub)
#pragma unroll
    for (int psub = 0; psub < 2; ++psub) {
      int OC = oc0 + ocq * 64 + osub * 32 + 4 * half;
      int pxc = psub * 32 + n;
      float* op = out + (((size_t)(b * NC + OC)) * 64 + py) * 64 + pxc;
#pragma unroll
      for (int reg = 0; reg < 16; ++reg) {
        int ocm = (reg & 3) + 8 * (reg >> 2);
        op[(size_t)ocm * 4096] = acc[osub][psub][reg];
      }
    }
}

extern "C" void kernel_launch(void* const* d_in, const int* in_sizes, int n_in,
                              void* d_out, int out_size, void* d_ws,
                              size_t ws_size, hipStream_t stream) {
  const float* x = (const float*)d_in[0];
  const float* dw = (const float*)d_in[1];
  const float* ka = (const float*)d_in[2];
  const int* fh = (const int*)d_in[3];
  const int* fw = (const int*)d_in[4];
  float* out = (float*)d_out;
  unsigned int* ws = (unsigned int*)d_ws;
  const unsigned short* specB = (const unsigned short*)d_ws;
  const unsigned short* Atw = (const unsigned short*)((char*)d_ws + 6291456);
  unsigned short* Ya = (unsigned short*)((char*)d_ws + 11010048);
  const unsigned short* T = (const unsigned short*)((char*)d_ws + 15925248);
  float* SW = (float*)d_ws;
  unsigned short* wBF = (unsigned short*)((char*)d_ws + WBF_BYTE);

  hipLaunchKernelGGL(prep_kernel, dim3(2841), dim3(256), 0, stream, dw, fh,
                     fw, ws);
  hipLaunchKernelGGL(fftA_kernel, dim3(12, 7, 8), dim3(256), 0, stream, Atw,
                     specB, Ya);
  hipLaunchKernelGGL(fftB_kernel, dim3(12, 12, KNUM), dim3(256), 0, stream, Ya,
                     T, SW);
  hipLaunchKernelGGL(wprep_kernel, dim3(768), dim3(256), 0, stream, ka, SW,
                     wBF);
  hipLaunchKernelGGL(conv_mfma_kernel, dim3(512), dim3(256), 0, stream, x,
                     wBF, out);
}